// Round 14
// baseline (163.179 us; speedup 1.0000x reference)
//
#include <hip/hip_runtime.h>
#include <stdint.h>

// Problem constants
#define BB 4
#define CC 256
#define HH 96
#define WW 96
#define HP 98      // halo-padded spatial dim
#define CP 264     // k-stride per x in ush (528 B; measured near-conflict-free b128 frags)
#define XT 32      // x positions per block
#define YT 6       // y rows per block (192 blocks -> single round, min A-traffic)
#define XE 34      // staged x entries (32 + 2 halo)

typedef __bf16 bf16x8 __attribute__((ext_vector_type(8)));
typedef __bf16 bf16x16 __attribute__((ext_vector_type(16)));
typedef float f32x4 __attribute__((ext_vector_type(4)));
typedef float f32x16 __attribute__((ext_vector_type(16)));

__device__ __forceinline__ uint16_t f2bf(float f) {
    uint32_t u = __float_as_uint(f);
    u += 0x7FFFu + ((u >> 16) & 1u);   // round-to-nearest-even
    return (uint16_t)(u >> 16);
}

// ---------------------------------------------------------------------------
// Pre-kernel 0: zero only the halo strips of cenT (y=0/97 rows, x=0/97 cols).
// ---------------------------------------------------------------------------
__global__ void zero_halo(uint16_t* __restrict__ cenT) {
    int idx = blockIdx.x * 256 + threadIdx.x;          // over 1552 pos * 33 uint4
    if (idx >= 1552 * 33) return;
    int p = idx / 33, q = idx - p * 33;
    int b = p / 388, s = p - b * 388;
    int y, x;
    if (s < 98)      { y = 0;       x = s; }
    else if (s < 196){ y = 97;      x = s - 98; }
    else if (s < 292){ x = 0;       y = s - 196 + 1; }
    else             { x = 97;      y = s - 292 + 1; }
    size_t o = (((size_t)b * HP + y) * HP + x) * CP + q * 8;
    *(uint4*)(cenT + o) = make_uint4(0u, 0u, 0u, 0u);
}

// ---------------------------------------------------------------------------
// Pre-kernel 1: cen (NCHW fp32) -> cenT [b][hy 98][hx 98][264] bf16 (interior).
// ---------------------------------------------------------------------------
__global__ void transpose_cen(const float* __restrict__ cen, uint16_t* __restrict__ cenT) {
    const int y = blockIdx.x, b = blockIdx.y, ch = blockIdx.z, tid = threadIdx.x;
    __shared__ uint16_t ldsX[128 * 100];

    #pragma unroll
    for (int i = 0; i < 12; ++i) {
        int f = i * 256 + tid;            // 0..3071: 128 c x 24 xq
        int c = f / 24, xq = f % 24;
        float4 v = *(const float4*)(cen + ((((size_t)b * CC + ch * 128 + c) * HH + y) * WW + xq * 4));
        uint2 pk;
        pk.x = (uint32_t)f2bf(v.x) | ((uint32_t)f2bf(v.y) << 16);
        pk.y = (uint32_t)f2bf(v.z) | ((uint32_t)f2bf(v.w) << 16);
        *(uint2*)(&ldsX[c * 100 + xq * 4]) = pk;
    }
    __syncthreads();
    #pragma unroll
    for (int i = 0; i < 6; ++i) {
        int t = i * 256 + tid;            // 0..1535: 96 x * 16 cq
        int x = t % 96, cq = t / 96;
        uint32_t w0, w1, w2, w3;
        w0 = (uint32_t)ldsX[(cq * 8 + 0) * 100 + x] | ((uint32_t)ldsX[(cq * 8 + 1) * 100 + x] << 16);
        w1 = (uint32_t)ldsX[(cq * 8 + 2) * 100 + x] | ((uint32_t)ldsX[(cq * 8 + 3) * 100 + x] << 16);
        w2 = (uint32_t)ldsX[(cq * 8 + 4) * 100 + x] | ((uint32_t)ldsX[(cq * 8 + 5) * 100 + x] << 16);
        w3 = (uint32_t)ldsX[(cq * 8 + 6) * 100 + x] | ((uint32_t)ldsX[(cq * 8 + 7) * 100 + x] << 16);
        size_t o = (((size_t)b * HP + (y + 1)) * HP + (x + 1)) * CP + ch * 128 + cq * 8;
        *(uint4*)(cenT + o) = make_uint4(w0, w1, w2, w3);
    }
}

// ---------------------------------------------------------------------------
// Pre-kernel 2: W3 [9][256 n][256 k] fp32 -> W3bf [g][t 8][ks 16][m 32][kh 2][8]
// A-frag (32x32x16: lane m holds k = kh*8 + j) for (g,t,ks) = 1 KiB contiguous.
// ---------------------------------------------------------------------------
__global__ void cvt_w3(const float* __restrict__ W3, uint16_t* __restrict__ W3bf) {
    int e = (blockIdx.x * 256 + threadIdx.x) * 4;   // 0..589823
    int g = e >> 16, n = (e >> 8) & 255, k = e & 255;
    float4 v = *(const float4*)(W3 + e);
    uint2 pk;
    pk.x = (uint32_t)f2bf(v.x) | ((uint32_t)f2bf(v.y) << 16);
    pk.y = (uint32_t)f2bf(v.z) | ((uint32_t)f2bf(v.w) << 16);
    size_t o = (size_t)(((g * 8 + (n >> 5)) * 16 + (k >> 4)) * 512)
             + (n & 31) * 16 + ((k >> 3) & 1) * 8 + (k & 7);
    *(uint2*)(W3bf + o) = pk;
}

// ---------------------------------------------------------------------------
// Main kernel R14 (= R13 resubmitted; R13 bench was an infra flake):
// grid (3 xt, 16 yt, 4 b) = 192 blocks, 512 thr (8 waves).
// Block tile: 192 positions (6 rows x 32 x) x 256 ch.
// Diagnosis (R1..R12): per-SIMD iteration slot is ~600 cyc INVARIANT across
// occupancy/depth/DMA/block-count; per-CU cost = ~152 cyc per wave-iter =
// 2 A-loads x 16 L1-missing lines x ~4.7 cyc/line -> L1 miss-processing
// throughput is the wall.  R12 duplicated each A-tile across the two p3
// wave-groups (L1 can't capture the drift-separated reuse).
// Fix: wave wv owns ch-tile wv (all 8 DISTINCT) x ALL 6 rows:
//   per ks = 1 A-load + 6 B ds_reads + 6 MFMAs  (A:MFMA density 3x R12,
//   block A-issue 2.25 -> 1.125 MB, L1 lines/CU halved -> ~36us floor).
// Regs: acc 6x16=96 + fin-bf16 48 + A-queue depth-2 16 + addr/transient ~60
// -> ~220 <= 256 -> 2 waves/SIMD.  LDS 143.6 + 12 = 155.9 KB (1 block/CU).
// Norm: 8 partials/position (one per ch-tile wave), ldsP[2][192][8] ping-pong,
// ONE barrier per g.
// ---------------------------------------------------------------------------
__global__ __launch_bounds__(512, 2)
void ecm_main(const float* __restrict__ cen, const uint16_t* __restrict__ cenT,
              const uint16_t* __restrict__ W3bf, float* __restrict__ out) {
    const int tid = threadIdx.x;
    const int wv = tid >> 6, lane = tid & 63, col = lane & 31, kh = lane >> 5;
    const int x0 = blockIdx.x * XT, y0 = blockIdx.y * YT, b = blockIdx.z;

    __shared__ __align__(16) uint16_t ldsA[8 * XE * CP];    // 143,616 B (8 halo rows)
    __shared__ __align__(16) float ldsP[2][192][8];         // ping-pong norm partials (12 KB)

    // g processed in dy-groups; dgOrd[idx] = reference g index, dx = idx%3 - 1.
    const int dgOrd[9] = {0, 1, 2, 7, 8, 3, 6, 5, 4};

    // Stage ALL 8 halo rows once (cenT halo rows y0 .. y0+7). Read-only after.
    for (int rr = 0; rr < 8; ++rr) {
        const uint4* gs = (const uint4*)(cenT + (((size_t)b * HP + (y0 + rr)) * HP + x0) * CP);
        uint4* ls = (uint4*)(ldsA + rr * XE * CP);
        for (int c = tid; c < XE * CP / 8; c += 512) ls[c] = gs[c];
    }
    __syncthreads();

    // wave owns ch-tile wv (16 KB A-stream per g, no cross-wave duplication)
    const uint16_t* wbA = W3bf + (size_t)wv * (16 * 512) + col * 16 + kh * 8;
    bf16x16 fin[6] = {};                           // packed bf16 fin (6 x 8 regs)

    #pragma unroll 1
    for (int idx = 0; idx < 9; ++idx) {
        const int g = dgOrd[idx], dg = idx / 3, dx = idx % 3 - 1;

        const uint16_t* wgA = wbA + (size_t)g * 65536;
        // wave's six rows: local rows 0..5; LDS row = rr + dg
        int a[6];
        #pragma unroll
        for (int rr = 0; rr < 6; ++rr)
            a[rr] = ((dg + rr) * XE + (col + dx + 1)) * CP + kh * 8;

        f32x16 acc[6] = {};

        // A: depth-2 rotating queue (static ks&1); B: read just-in-time
        // (compiler hoists/pipelines the 6 ds_reads within the unrolled iter).
        bf16x8 qA[2];
        qA[0] = *(const bf16x8*)(wgA);
        qA[1] = *(const bf16x8*)(wgA + 512);

        #pragma unroll
        for (int ks = 0; ks < 16; ++ks) {
            bf16x8 wa = qA[ks & 1];
            if (ks + 2 < 16) qA[ks & 1] = *(const bf16x8*)(wgA + (ks + 2) * 512);
            bf16x8 br[6];
            #pragma unroll
            for (int rr = 0; rr < 6; ++rr)
                br[rr] = *(const bf16x8*)(ldsA + a[rr] + ks * 16);
            __builtin_amdgcn_s_setprio(1);
            #pragma unroll
            for (int rr = 0; rr < 6; ++rr)
                acc[rr] = __builtin_amdgcn_mfma_f32_32x32x16_bf16(wa, br[rr], acc[rr], 0, 0, 0);
            __builtin_amdgcn_s_setprio(0);
        }

        // Per-position ||Y||^2 partial over this wave's 32 ch (its tile).
        #pragma unroll
        for (int rr = 0; rr < 6; ++rr) {
            float t = 0.f;
            #pragma unroll
            for (int r = 0; r < 16; ++r) t += acc[rr][r] * acc[rr][r];
            t += __shfl_xor(t, 32, 64);
            if (kh == 0) ldsP[idx & 1][rr * 32 + col][wv] = t;
        }
        __syncthreads();   // the ONLY barrier per g (ping-pong covers WAR)

        const float sgn = (g == 8) ? 1.f : -1.f;
        #pragma unroll
        for (int rr = 0; rr < 6; ++rr) {
            f32x4 pa = *(const f32x4*)&ldsP[idx & 1][rr * 32 + col][0];
            f32x4 pb = *(const f32x4*)&ldsP[idx & 1][rr * 32 + col][4];
            float n = pa[0] + pa[1] + pa[2] + pa[3] + pb[0] + pb[1] + pb[2] + pb[3];
            float sc = sgn / fmaxf(sqrtf(n), 1e-12f);
            #pragma unroll
            for (int r = 0; r < 16; ++r)
                fin[rr][r] = (__bf16)((float)fin[rr][r] + acc[rr][r] * sc);
        }
    }

    // Epilogue: out = fin + cen. D row->ch: (reg&3) + 8*(reg>>2) + 4*kh
    // (+32*wv base); row = y0 + rr.
    #pragma unroll
    for (int rr = 0; rr < 6; ++rr) {
        #pragma unroll
        for (int r = 0; r < 16; ++r) {
            int ch = wv * 32 + (r & 3) + 8 * (r >> 2) + 4 * kh;
            size_t o = (((size_t)b * CC + ch) * HH + (y0 + rr)) * WW + (x0 + col);
            out[o] = (float)fin[rr][r] + cen[o];
        }
    }
}

extern "C" void kernel_launch(void* const* d_in, const int* in_sizes, int n_in,
                              void* d_out, int out_size, void* d_ws, size_t ws_size,
                              hipStream_t stream) {
    const float* cen = (const float*)d_in[0];
    // d_in[1] = W1, d_in[2] = W2: dead code (softmax over size-1 axis == 1.0)
    const float* W3 = (const float*)d_in[3];
    float* out = (float*)d_out;

    uint16_t* cenT = (uint16_t*)d_ws;                         // [4][98][98][264] bf16
    const size_t cenT_elems = (size_t)BB * HP * HP * CP;
    uint16_t* W3bf = cenT + cenT_elems;                       // [9][8][16][512] bf16

    zero_halo<<<201, 256, 0, stream>>>(cenT);
    transpose_cen<<<dim3(HH, BB, 2), 256, 0, stream>>>(cen, cenT);
    cvt_w3<<<576, 256, 0, stream>>>(W3, W3bf);
    ecm_main<<<dim3(3, 16, 4), 512, 0, stream>>>(cen, cenT, W3bf, out);
}